// Round 4
// baseline (5416.814 us; speedup 1.0000x reference)
//
#include <hip/hip_runtime.h>
#include <math.h>

#define BB 256
#define TT 128
#define NN 512
#define HH 512
#define G3 1536
#define SLAB (HH * BB)     // 131072: one [512][256] or [256][512] slab (elems)
#define XSLAB (G3 * BB)    // 393216: one [1536][256] xi slab (floats)

typedef __attribute__((ext_vector_type(8))) short bf16x8;   // 8 bf16 = 4 VGPRs
typedef __attribute__((ext_vector_type(4))) float f32x4;

__device__ __forceinline__ unsigned short bf16_rne(float f) {
    union { float f; unsigned int u; } v; v.f = f;
    unsigned int r = (v.u + 0x7fffu + ((v.u >> 16) & 1u)) >> 16;
    return (unsigned short)r;
}
__device__ __forceinline__ float bf16_tof(unsigned short h) {
    union { float f; unsigned int u; } v; v.u = ((unsigned int)h) << 16;
    return v.f;
}
__device__ __forceinline__ float sigm(float v) { return 1.f / (1.f + expf(-v)); }

__global__ void zero_kernel(float* p, int n) {
    int i = blockIdx.x * blockDim.x + threadIdx.x;
    if (i < n) p[i] = 0.f;
}

// fp32 [n] -> hi/lo bf16 split
__global__ __launch_bounds__(256) void convert_split(
    const float* __restrict__ in, unsigned short* __restrict__ hi,
    unsigned short* __restrict__ lo, int n) {
    int i = (blockIdx.x * 256 + threadIdx.x) * 4;
    if (i >= n) return;
    float4 v = *(const float4*)(in + i);
    float f[4] = {v.x, v.y, v.z, v.w};
    ushort4 h, l;
    unsigned short* hp = (unsigned short*)&h;
    unsigned short* lp = (unsigned short*)&l;
#pragma unroll
    for (int q = 0; q < 4; ++q) {
        unsigned short hh = bf16_rne(f[q]);
        hp[q] = hh;
        lp[q] = bf16_rne(f[q] - bf16_tof(hh));
    }
    *(ushort4*)(hi + i) = h;
    *(ushort4*)(lo + i) = l;
}

// ---- fused-step device sections ----------------------------------------

// xi GEMM section: out[g][b] = sum_k W[g][k]*Brow[b][k] + bias[g]
// tile 64g x 32b, grid 24 x 8 = 192 blocks, 3-term split-bf16 MFMA
__device__ __forceinline__ void xi_block(int bi,
    const unsigned short* __restrict__ Wh, const unsigned short* __restrict__ Wl,
    const unsigned short* __restrict__ Bh, const unsigned short* __restrict__ Bl,
    const float* __restrict__ bias, float* __restrict__ out, unsigned char* smem) {
    unsigned short (*As)[64][40] = (unsigned short (*)[64][40])smem;             // 10240 B
    unsigned short (*Bs)[32][40] = (unsigned short (*)[32][40])(smem + 10240);   // 5120 B
    const int tid = threadIdx.x;
    const int lane = tid & 63, w = tid >> 6;
    const int l15 = lane & 15, l4 = lane >> 4;
    const int g0 = (bi >> 3) * 64, b0 = (bi & 7) * 32;
    f32x4 acc0 = {0, 0, 0, 0}, acc1 = {0, 0, 0, 0};
    for (int kc = 0; kc < 512; kc += 32) {
        uint4 av[2], bv;
#pragma unroll
        for (int i = 0; i < 2; ++i) {
            int idx = tid + 256 * i;
            int half = idx >> 8, rem = idx & 255;
            int row = rem >> 2, quad = rem & 3;
            const unsigned short* srcp = half ? Wl : Wh;
            av[i] = *(const uint4*)(srcp + (size_t)(g0 + row) * 512 + kc + quad * 8);
        }
        {
            int half = tid >> 7, rem = tid & 127;
            int row = rem >> 2, quad = rem & 3;
            const unsigned short* srcp = half ? Bl : Bh;
            bv = *(const uint4*)(srcp + (size_t)(b0 + row) * 512 + kc + quad * 8);
        }
        __syncthreads();
#pragma unroll
        for (int i = 0; i < 2; ++i) {
            int idx = tid + 256 * i;
            int half = idx >> 8, rem = idx & 255;
            int row = rem >> 2, quad = rem & 3;
            *(uint4*)&As[half][row][quad * 8] = av[i];
        }
        {
            int half = tid >> 7, rem = tid & 127;
            int row = rem >> 2, quad = rem & 3;
            *(uint4*)&Bs[half][row][quad * 8] = bv;
        }
        __syncthreads();
        bf16x8 ah = *(const bf16x8*)&As[0][w * 16 + l15][l4 * 8];
        bf16x8 al = *(const bf16x8*)&As[1][w * 16 + l15][l4 * 8];
        bf16x8 bh0 = *(const bf16x8*)&Bs[0][l15][l4 * 8];
        bf16x8 bl0 = *(const bf16x8*)&Bs[1][l15][l4 * 8];
        bf16x8 bh1 = *(const bf16x8*)&Bs[0][16 + l15][l4 * 8];
        bf16x8 bl1 = *(const bf16x8*)&Bs[1][16 + l15][l4 * 8];
        acc0 = __builtin_amdgcn_mfma_f32_16x16x32_bf16(ah, bh0, acc0, 0, 0, 0);
        acc0 = __builtin_amdgcn_mfma_f32_16x16x32_bf16(ah, bl0, acc0, 0, 0, 0);
        acc0 = __builtin_amdgcn_mfma_f32_16x16x32_bf16(al, bh0, acc0, 0, 0, 0);
        acc1 = __builtin_amdgcn_mfma_f32_16x16x32_bf16(ah, bh1, acc1, 0, 0, 0);
        acc1 = __builtin_amdgcn_mfma_f32_16x16x32_bf16(ah, bl1, acc1, 0, 0, 0);
        acc1 = __builtin_amdgcn_mfma_f32_16x16x32_bf16(al, bh1, acc1, 0, 0, 0);
    }
#pragma unroll
    for (int r = 0; r < 4; ++r) {
        int g = g0 + w * 16 + l4 * 4 + r;
        float bvs = bias[g];
        out[(size_t)g * 256 + b0 + l15] = acc0[r] + bvs;
        out[(size_t)g * 256 + b0 + 16 + l15] = acc1[r] + bvs;
    }
}

// recurrent step section: gh = h@Whh^T (+bhh), gates, h-update.
// tile 32j x 32b (3 gate panels), grid 16 x 8 = 128 blocks.
__device__ __forceinline__ void rec_block(int bi,
    const unsigned short* __restrict__ Wh, const unsigned short* __restrict__ Wl,
    const unsigned short* __restrict__ Hbh, const unsigned short* __restrict__ Hbl,
    const float* __restrict__ xi, const float* __restrict__ bhh,
    const float* __restrict__ hprevf, float* __restrict__ hnewf,
    unsigned short* __restrict__ Hnh, unsigned short* __restrict__ Hnl,
    unsigned char* smem) {
    unsigned short (*As)[96][40] = (unsigned short (*)[96][40])smem;             // 15360 B
    unsigned short (*Bs)[32][40] = (unsigned short (*)[32][40])(smem + 15360);   // 5120 B
    float (*hl)[36] = (float (*)[36])(smem + 20480);                             // 4608 B
    const int tid = threadIdx.x;
    const int lane = tid & 63, w = tid >> 6;
    const int l15 = lane & 15, l4 = lane >> 4;
    const int jf = w >> 1, bf = w & 1;
    const int j0 = (bi >> 3) * 32, b0 = (bi & 7) * 32;
    f32x4 aR = {0, 0, 0, 0}, aZ = aR, aN = aR;
    for (int kc = 0; kc < 512; kc += 32) {
        uint4 av[3], bv;
#pragma unroll
        for (int i = 0; i < 3; ++i) {
            int idx = tid + 256 * i;                 // 0..767
            int half = idx >= 384;
            int rem = half ? idx - 384 : idx;
            int row = rem >> 2, quad = rem & 3;      // row 0..95
            int gate = row >> 5, rl = row & 31;
            const unsigned short* srcp = half ? Wl : Wh;
            av[i] = *(const uint4*)(srcp + (size_t)(gate * 512 + j0 + rl) * 512 + kc + quad * 8);
        }
        {
            int half = tid >> 7, rem = tid & 127;
            int row = rem >> 2, quad = rem & 3;
            const unsigned short* srcp = half ? Hbl : Hbh;
            bv = *(const uint4*)(srcp + (size_t)(b0 + row) * 512 + kc + quad * 8);
        }
        __syncthreads();
#pragma unroll
        for (int i = 0; i < 3; ++i) {
            int idx = tid + 256 * i;
            int half = idx >= 384;
            int rem = half ? idx - 384 : idx;
            int row = rem >> 2, quad = rem & 3;
            *(uint4*)&As[half][row][quad * 8] = av[i];
        }
        {
            int half = tid >> 7, rem = tid & 127;
            int row = rem >> 2, quad = rem & 3;
            *(uint4*)&Bs[half][row][quad * 8] = bv;
        }
        __syncthreads();
        bf16x8 bh = *(const bf16x8*)&Bs[0][bf * 16 + l15][l4 * 8];
        bf16x8 bl = *(const bf16x8*)&Bs[1][bf * 16 + l15][l4 * 8];
#pragma unroll
        for (int g = 0; g < 3; ++g) {
            bf16x8 ah = *(const bf16x8*)&As[0][g * 32 + jf * 16 + l15][l4 * 8];
            bf16x8 al = *(const bf16x8*)&As[1][g * 32 + jf * 16 + l15][l4 * 8];
            f32x4& ac = (g == 0 ? aR : (g == 1 ? aZ : aN));
            ac = __builtin_amdgcn_mfma_f32_16x16x32_bf16(ah, bh, ac, 0, 0, 0);
            ac = __builtin_amdgcn_mfma_f32_16x16x32_bf16(ah, bl, ac, 0, 0, 0);
            ac = __builtin_amdgcn_mfma_f32_16x16x32_bf16(al, bh, ac, 0, 0, 0);
        }
    }
#pragma unroll
    for (int r = 0; r < 4; ++r) {
        int jl = jf * 16 + l4 * 4 + r;
        int jrow = j0 + jl;
        int b = b0 + bf * 16 + l15;
        float ghr = aR[r] + bhh[jrow];
        float ghz = aZ[r] + bhh[512 + jrow];
        float ghn = aN[r] + bhh[1024 + jrow];
        float xr = xi[(size_t)jrow * 256 + b];
        float xz = xi[(size_t)(512 + jrow) * 256 + b];
        float xn = xi[(size_t)(1024 + jrow) * 256 + b];
        float hp = hprevf[(size_t)jrow * 256 + b];
        float rr = sigm(xr + ghr);
        float zz = sigm(xz + ghz);
        float nn = tanhf(xn + rr * ghn);
        float hv = (1.f - zz) * nn + zz * hp;
        hnewf[(size_t)jrow * 256 + b] = hv;
        hl[jl][bf * 16 + l15] = hv;
    }
    __syncthreads();
    {   // bf16 split + transpose to [b][k] rows
        int bl_ = tid >> 3;   // 0..31
        int kg = tid & 7;     // 0..7 -> 4 k each
        ushort4 hq, lq;
        unsigned short* hqp = (unsigned short*)&hq;
        unsigned short* lqp = (unsigned short*)&lq;
#pragma unroll
        for (int i = 0; i < 4; ++i) {
            float v = hl[kg * 4 + i][bl_];
            unsigned short hh = bf16_rne(v);
            hqp[i] = hh;
            lqp[i] = bf16_rne(v - bf16_tof(hh));
        }
        *(ushort4*)(Hnh + (size_t)(b0 + bl_) * 512 + j0 + kg * 4) = hq;
        *(ushort4*)(Hnl + (size_t)(b0 + bl_) * 512 + j0 + kg * 4) = lq;
    }
}

// x[t] -> bf16 split rows [b][k]; 32 blocks x 256 thr x 16 elems
__device__ __forceinline__ void xc_block(int bi, const float* __restrict__ x, int t,
    unsigned short* __restrict__ Xh, unsigned short* __restrict__ Xl) {
    int e = (bi * 256 + threadIdx.x) * 16;
    int b = e >> 9, k0 = e & 511;
    const float* src = x + ((size_t)b * TT + t) * NN + k0;
#pragma unroll
    for (int q = 0; q < 4; ++q) {
        float4 v = *(const float4*)(src + q * 4);
        float f[4] = {v.x, v.y, v.z, v.w};
        ushort4 h, l;
        unsigned short* hp = (unsigned short*)&h;
        unsigned short* lp = (unsigned short*)&l;
#pragma unroll
        for (int u = 0; u < 4; ++u) {
            unsigned short hh = bf16_rne(f[u]);
            hp[u] = hh;
            lp[u] = bf16_rne(f[u] - bf16_tof(hh));
        }
        *(ushort4*)(Xh + (size_t)b * 512 + k0 + q * 4) = h;
        *(ushort4*)(Xl + (size_t)b * 512 + k0 + q * 4) = l;
    }
}

// One pipelined global step: sections REC0(t=s) REC1(t=s-2) XI1(t=s-1) XI0(t=s+1) XC(t=s+2)
__global__ __launch_bounds__(256) void step_fused(
    int s, const float* __restrict__ x,
    const unsigned short* W0ih_h, const unsigned short* W0ih_l,
    const unsigned short* W0hh_h, const unsigned short* W0hh_l,
    const unsigned short* W1ih_h, const unsigned short* W1ih_l,
    const unsigned short* W1hh_h, const unsigned short* W1hh_l,
    const float* bih0, const float* bhh0, const float* bih1, const float* bhh1,
    unsigned short* Xh, unsigned short* Xl,
    unsigned short* H0h, unsigned short* H0l,
    unsigned short* H1h, unsigned short* H1l,
    float* xi0, float* xi1, float* h0f, float* h1f) {
    __shared__ __align__(16) unsigned char smem[25600];
    const int bi = blockIdx.x;
    if (bi < 128) {                       // REC0, t = s
        int t = s;
        if (t < 0 || t > 127) return;
        int sp = (t - 1) & 1, sn = t & 1;
        rec_block(bi, W0hh_h, W0hh_l,
                  H0h + (size_t)sp * SLAB, H0l + (size_t)sp * SLAB,
                  xi0 + (size_t)sn * XSLAB, bhh0,
                  h0f + (size_t)sp * SLAB, h0f + (size_t)sn * SLAB,
                  H0h + (size_t)sn * SLAB, H0l + (size_t)sn * SLAB, smem);
    } else if (bi < 256) {                // REC1, t = s-2
        int t = s - 2;
        if (t < 0 || t > 127) return;
        int sp = (t - 1) & 1, sn = t & 1;
        rec_block(bi - 128, W1hh_h, W1hh_l,
                  H1h + (size_t)sp * SLAB, H1l + (size_t)sp * SLAB,
                  xi1 + (size_t)sn * XSLAB, bhh1,
                  h1f + (size_t)sp * SLAB, h1f + (size_t)sn * SLAB,
                  H1h + (size_t)sn * SLAB, H1l + (size_t)sn * SLAB, smem);
    } else if (bi < 448) {                // XI1, t = s-1: xi1[t] = W1ih x h0bf[t]
        int t = s - 1;
        if (t < 0 || t > 127) return;
        int sl = t & 1;
        xi_block(bi - 256, W1ih_h, W1ih_l,
                 H0h + (size_t)sl * SLAB, H0l + (size_t)sl * SLAB,
                 bih1, xi1 + (size_t)sl * XSLAB, smem);
    } else if (bi < 640) {                // XI0, t = s+1: xi0[t] = W0ih x Xbf[t]
        int t = s + 1;
        if (t < 0 || t > 127) return;
        int sl = t & 1;
        xi_block(bi - 448, W0ih_h, W0ih_l,
                 Xh + (size_t)sl * SLAB, Xl + (size_t)sl * SLAB,
                 bih0, xi0 + (size_t)sl * XSLAB, smem);
    } else {                              // XC, t = s+2
        int t = s + 2;
        if (t < 0 || t > 127) return;
        int sl = t & 1;
        xc_block(bi - 640, x, t, Xh + (size_t)sl * SLAB, Xl + (size_t)sl * SLAB);
    }
}

// hT[512][256] -> h[256][512]
__global__ __launch_bounds__(256) void hT_to_h(
    const float* __restrict__ hT, float* __restrict__ h) {
    __shared__ float tb[64][65];
    const int tid = threadIdx.x;
    const int k0 = blockIdx.x * 64, b0 = blockIdx.y * 64;
#pragma unroll
    for (int i = 0; i < 4; ++i) {
        int r = (tid >> 4) + 16 * i;
        int c = (tid & 15) * 4;
        float4 v = *(const float4*)(hT + (size_t)(k0 + r) * 256 + b0 + c);
        tb[c + 0][r] = v.x; tb[c + 1][r] = v.y; tb[c + 2][r] = v.z; tb[c + 3][r] = v.w;
    }
    __syncthreads();
#pragma unroll
    for (int i = 0; i < 4; ++i) {
        int r = (tid >> 4) + 16 * i;
        int c = (tid & 15) * 4;
        float4 v;
        v.x = tb[r][c]; v.y = tb[r][c + 1]; v.z = tb[r][c + 2]; v.w = tb[r][c + 3];
        *(float4*)(h + (size_t)(b0 + r) * 512 + k0 + c) = v;
    }
}

__device__ __forceinline__ float blockReduceSum(float v, float* tmp) {
    __syncthreads();
#pragma unroll
    for (int o = 32; o; o >>= 1) v += __shfl_down(v, o);
    if ((threadIdx.x & 63) == 0) tmp[threadIdx.x >> 6] = v;
    __syncthreads();
    if (threadIdx.x == 0) tmp[4] = tmp[0] + tmp[1] + tmp[2] + tmp[3];
    __syncthreads();
    return tmp[4];
}

__device__ __forceinline__ float blockReduceMax(float v, float* tmp) {
    __syncthreads();
#pragma unroll
    for (int o = 32; o; o >>= 1) v = fmaxf(v, __shfl_down(v, o));
    if ((threadIdx.x & 63) == 0) tmp[threadIdx.x >> 6] = v;
    __syncthreads();
    if (threadIdx.x == 0) tmp[4] = fmaxf(fmaxf(tmp[0], tmp[1]), fmaxf(tmp[2], tmp[3]));
    __syncthreads();
    return tmp[4];
}

__global__ __launch_bounds__(256) void head_kernel(
    const float* __restrict__ h1, const float* __restrict__ fcw,
    const float* __restrict__ fcb, float* __restrict__ out) {
    __shared__ __align__(16) float hrow[512];
    __shared__ float wv[512];
    __shared__ float ov[512];
    __shared__ float tmp[8];
    const int b = blockIdx.x, tid = threadIdx.x;
    hrow[tid]       = h1[(size_t)b * 512 + tid];
    hrow[tid + 256] = h1[(size_t)b * 512 + 256 + tid];
    __syncthreads();

    float s[2];
#pragma unroll
    for (int q = 0; q < 2; ++q) {
        int n = tid + q * 256;
        const float* wr = fcw + (size_t)n * 512;
        float acc = 0.f;
        for (int k = 0; k < 512; k += 4) {
            float4 wq = *(const float4*)(wr + k);
            acc += wq.x * hrow[k] + wq.y * hrow[k + 1] + wq.z * hrow[k + 2] + wq.w * hrow[k + 3];
        }
        float l = acc + fcb[n];
        s[q] = l / (1.f + expf(-l));
    }

    float mx = blockReduceMax(fmaxf(s[0], s[1]), tmp);
    float e0 = expf(s[0] - mx), e1 = expf(s[1] - mx);
    float sum = blockReduceSum(e0 + e1, tmp);
    float w0 = e0 / sum, w1 = e1 / sum;

    ov[tid] = w0;       ov[tid + 256] = w1;
    wv[tid]       = fminf(fmaxf(w0, 0.f), 0.1f);
    wv[tid + 256] = fminf(fmaxf(w1, 0.f), 0.1f);
    __syncthreads();

    for (int it = 0; it < 32; ++it) {
        float wc0 = wv[tid], wc1 = wv[tid + 256];
        float o0 = ov[tid], o1 = ov[tid + 256];
        float leftover = blockReduceSum((o0 - wc0) + (o1 - wc1), tmp);
        float n0 = (wc0 != 0.1f) ? wc0 : 0.f;
        float n1 = (wc1 != 0.1f) ? wc1 : 0.f;
        float denom = blockReduceSum(n0 + n1, tmp);
        float w20 = wc0 + leftover * n0 / denom;
        float w21 = wc1 + leftover * n1 / denom;
        float fl = ((w20 > 0.1f) || (w21 > 0.1f)) ? 1.f : 0.f;
        bool again = blockReduceSum(fl, tmp) > 0.f;
        __syncthreads();
        ov[tid] = w20; ov[tid + 256] = w21;
        wv[tid]       = again ? fminf(fmaxf(w20, 0.f), 0.1f) : w20;
        wv[tid + 256] = again ? fminf(fmaxf(w21, 0.f), 0.1f) : w21;
        __syncthreads();
        if (!again) break;
    }

    out[(size_t)b * 512 + tid]       = wv[tid];
    out[(size_t)b * 512 + 256 + tid] = wv[tid + 256];
}

extern "C" void kernel_launch(void* const* d_in, const int* in_sizes, int n_in,
                              void* d_out, int out_size, void* d_ws, size_t ws_size,
                              hipStream_t stream) {
    const float* x    = (const float*)d_in[0];
    const float* Wih0 = (const float*)d_in[1];
    const float* Whh0 = (const float*)d_in[2];
    const float* bih0 = (const float*)d_in[3];
    const float* bhh0 = (const float*)d_in[4];
    const float* Wih1 = (const float*)d_in[5];
    const float* Whh1 = (const float*)d_in[6];
    const float* bih1 = (const float*)d_in[7];
    const float* bhh1 = (const float*)d_in[8];
    const float* fcw  = (const float*)d_in[9];
    const float* fcb  = (const float*)d_in[10];
    float* out = (float*)d_out;

    const size_t WHALF = (size_t)G3 * HH;   // 786432 ushorts per weight half
    unsigned short* base = (unsigned short*)d_ws;
    unsigned short* W0ih_h = base;
    unsigned short* W0ih_l = W0ih_h + WHALF;
    unsigned short* W0hh_h = W0ih_l + WHALF;
    unsigned short* W0hh_l = W0hh_h + WHALF;
    unsigned short* W1ih_h = W0hh_l + WHALF;
    unsigned short* W1ih_l = W1ih_h + WHALF;
    unsigned short* W1hh_h = W1ih_l + WHALF;
    unsigned short* W1hh_l = W1hh_h + WHALF;
    unsigned short* Xh  = W1hh_l + WHALF;       // [2][SLAB]
    unsigned short* Xl  = Xh + 2 * (size_t)SLAB;
    unsigned short* H0h = Xl + 2 * (size_t)SLAB;
    unsigned short* H0l = H0h + 2 * (size_t)SLAB;
    unsigned short* H1h = H0l + 2 * (size_t)SLAB;
    unsigned short* H1l = H1h + 2 * (size_t)SLAB;
    float* fbase = (float*)(H1l + 2 * (size_t)SLAB);
    float* xi0 = fbase;                          // [2][XSLAB]
    float* xi1 = xi0 + 2 * (size_t)XSLAB;
    float* h0f = xi1 + 2 * (size_t)XSLAB;        // [2][SLAB]
    float* h1f = h0f + 2 * (size_t)SLAB;
    float* h1n = h1f + 2 * (size_t)SLAB;         // [256][512] for head

    // weight converts
    const int wn = G3 * HH;
    convert_split<<<wn / 1024, 256, 0, stream>>>(Wih0, W0ih_h, W0ih_l, wn);
    convert_split<<<wn / 1024, 256, 0, stream>>>(Whh0, W0hh_h, W0hh_l, wn);
    convert_split<<<wn / 1024, 256, 0, stream>>>(Wih1, W1ih_h, W1ih_l, wn);
    convert_split<<<wn / 1024, 256, 0, stream>>>(Whh1, W1hh_h, W1hh_l, wn);
    // zero initial states (slot 1 = (t=-1)&1)
    zero_kernel<<<SLAB / 256, 256, 0, stream>>>(h0f + SLAB, SLAB);
    zero_kernel<<<SLAB / 256, 256, 0, stream>>>(h1f + SLAB, SLAB);
    zero_kernel<<<(SLAB / 2) / 256, 256, 0, stream>>>((float*)(H0h + SLAB), SLAB / 2);
    zero_kernel<<<(SLAB / 2) / 256, 256, 0, stream>>>((float*)(H0l + SLAB), SLAB / 2);
    zero_kernel<<<(SLAB / 2) / 256, 256, 0, stream>>>((float*)(H1h + SLAB), SLAB / 2);
    zero_kernel<<<(SLAB / 2) / 256, 256, 0, stream>>>((float*)(H1l + SLAB), SLAB / 2);

    for (int s = -2; s <= 129; ++s) {
        step_fused<<<672, 256, 0, stream>>>(s, x,
            W0ih_h, W0ih_l, W0hh_h, W0hh_l, W1ih_h, W1ih_l, W1hh_h, W1hh_l,
            bih0, bhh0, bih1, bhh1,
            Xh, Xl, H0h, H0l, H1h, H1l, xi0, xi1, h0f, h1f);
    }

    // final h1 is t=127 -> slot 1
    hT_to_h<<<dim3(8, 4), 256, 0, stream>>>(h1f + SLAB, h1n);
    head_kernel<<<BB, 256, 0, stream>>>(h1n, fcw, fcb, out);
}